// Round 6
// baseline (1519.605 us; speedup 1.0000x reference)
//
#include <hip/hip_runtime.h>
#include <math.h>

#define B_ 4
#define T_ 1024
#define C_ 1024
#define H_ 16
#define D_ 64
#define BH_ 64
#define TOPK_ 256

__device__ __forceinline__ unsigned int f2u(float f) {
    unsigned int u = __float_as_uint(f);
    return (u & 0x80000000u) ? ~u : (u | 0x80000000u);
}

// ---------- QKV projection: out[b,h,t,d] = bias[o] + sum_c x[b,t,c]*w[o,c]*m[o,c] ----------
// 128x128 tile, BK=16, 8x8 micro-tile (split 4+4 columns/rows to avoid LDS bank conflicts)
__global__ __launch_bounds__(256) void k_qkv(
    const float* __restrict__ x,
    const float* __restrict__ wq, const float* __restrict__ mq, const float* __restrict__ bq,
    const float* __restrict__ wk, const float* __restrict__ mk, const float* __restrict__ bk,
    const float* __restrict__ wv, const float* __restrict__ mv, const float* __restrict__ bv,
    float* __restrict__ Qo, float* __restrict__ Ko, float* __restrict__ Vo)
{
    const int z = blockIdx.z;
    const float* W    = z == 0 ? wq : (z == 1 ? wk : wv);
    const float* M    = z == 0 ? mq : (z == 1 ? mk : mv);
    const float* bias = z == 0 ? bq : (z == 1 ? bk : bv);
    float* out        = z == 0 ? Qo : (z == 1 ? Ko : Vo);

    __shared__ float As[16][132];
    __shared__ float Bs[16][132];

    const int tid = threadIdx.x;
    const int tx = tid & 15;
    const int ty = tid >> 4;
    const int mBase = blockIdx.y * 128;
    const int nBase = blockIdx.x * 128;

    float acc[8][8];
    #pragma unroll
    for (int i = 0; i < 8; ++i)
        #pragma unroll
        for (int j = 0; j < 8; ++j) acc[i][j] = 0.0f;

    for (int k0 = 0; k0 < C_; k0 += 16) {
        #pragma unroll
        for (int p = 0; p < 2; ++p) {
            int f = p * 256 + tid;
            int row = f >> 2;            // 0..127
            int kc  = (f & 3) * 4;       // 0,4,8,12
            float4 av = *reinterpret_cast<const float4*>(x + (size_t)(mBase + row) * C_ + k0 + kc);
            size_t boff = (size_t)(nBase + row) * C_ + k0 + kc;
            float4 wv4 = *reinterpret_cast<const float4*>(W + boff);
            float4 mv4 = *reinterpret_cast<const float4*>(M + boff);
            As[kc + 0][row] = av.x; As[kc + 1][row] = av.y;
            As[kc + 2][row] = av.z; As[kc + 3][row] = av.w;
            Bs[kc + 0][row] = wv4.x * mv4.x; Bs[kc + 1][row] = wv4.y * mv4.y;
            Bs[kc + 2][row] = wv4.z * mv4.z; Bs[kc + 3][row] = wv4.w * mv4.w;
        }
        __syncthreads();
        #pragma unroll
        for (int kk = 0; kk < 16; ++kk) {
            float4 aLo = *reinterpret_cast<const float4*>(&As[kk][ty * 4]);
            float4 aHi = *reinterpret_cast<const float4*>(&As[kk][64 + ty * 4]);
            float4 bLo = *reinterpret_cast<const float4*>(&Bs[kk][tx * 4]);
            float4 bHi = *reinterpret_cast<const float4*>(&Bs[kk][64 + tx * 4]);
            float a[8] = {aLo.x, aLo.y, aLo.z, aLo.w, aHi.x, aHi.y, aHi.z, aHi.w};
            float b[8] = {bLo.x, bLo.y, bLo.z, bLo.w, bHi.x, bHi.y, bHi.z, bHi.w};
            #pragma unroll
            for (int i = 0; i < 8; ++i)
                #pragma unroll
                for (int j = 0; j < 8; ++j)
                    acc[i][j] += a[i] * b[j];
        }
        __syncthreads();
    }

    #pragma unroll
    for (int ih = 0; ih < 2; ++ih) {
        #pragma unroll
        for (int i = 0; i < 4; ++i) {
            int m = mBase + ih * 64 + ty * 4 + i;
            int b_i = m >> 10;
            int t_i = m & 1023;
            #pragma unroll
            for (int jh = 0; jh < 2; ++jh) {
                int o0 = nBase + jh * 64 + tx * 4;
                float4 r;
                r.x = acc[ih * 4 + i][jh * 4 + 0] + bias[o0 + 0];
                r.y = acc[ih * 4 + i][jh * 4 + 1] + bias[o0 + 1];
                r.z = acc[ih * 4 + i][jh * 4 + 2] + bias[o0 + 2];
                r.w = acc[ih * 4 + i][jh * 4 + 3] + bias[o0 + 3];
                *reinterpret_cast<float4*>(out + (((size_t)b_i * H_ + (o0 >> 6)) * T_ + t_i) * D_ + (o0 & 63)) = r;
            }
        }
    }
}

// ---------- Vsum[bh,d] = sum_t V[bh,t,d] ----------
__global__ __launch_bounds__(64) void k_vsum(const float* __restrict__ V, float* __restrict__ Vsum)
{
    const int bh = blockIdx.x;
    const int d  = threadIdx.x;
    const float* p = V + (size_t)bh * T_ * D_ + d;
    float s = 0.0f;
    for (int t = 0; t < T_; ++t) s += p[(size_t)t * D_];
    Vsum[bh * D_ + d] = s;
}

// ---------- att[l,i,j] = (Q[g,i,:] . K[g,j,:]) / 8 ----------  (64x64 tile, K=64 single shot)
__global__ __launch_bounds__(256) void k_qk(const float* __restrict__ Q, const float* __restrict__ Kt,
                                            float* __restrict__ att, int bh0)
{
    const int l = blockIdx.z;
    const int g = bh0 + l;
    const float* Qb = Q  + (size_t)g * T_ * D_;
    const float* Kb = Kt + (size_t)g * T_ * D_;
    const int iBase = blockIdx.y * 64;
    const int jBase = blockIdx.x * 64;

    __shared__ float As[64][68];   // [d][i]
    __shared__ float Bs[64][68];   // [d][j]

    const int tid = threadIdx.x;
    const int tx = tid & 15, ty = tid >> 4;

    #pragma unroll
    for (int p = 0; p < 4; ++p) {
        int f = p * 256 + tid;
        int row = f >> 4;          // 0..63
        int c0  = (f & 15) * 4;    // 0..60
        float4 qa = *reinterpret_cast<const float4*>(Qb + (size_t)(iBase + row) * D_ + c0);
        float4 ka = *reinterpret_cast<const float4*>(Kb + (size_t)(jBase + row) * D_ + c0);
        As[c0 + 0][row] = qa.x; As[c0 + 1][row] = qa.y; As[c0 + 2][row] = qa.z; As[c0 + 3][row] = qa.w;
        Bs[c0 + 0][row] = ka.x; Bs[c0 + 1][row] = ka.y; Bs[c0 + 2][row] = ka.z; Bs[c0 + 3][row] = ka.w;
    }
    __syncthreads();

    float acc[4][4] = {{0.0f}};
    #pragma unroll 8
    for (int kk = 0; kk < 64; ++kk) {
        float4 a4 = *reinterpret_cast<const float4*>(&As[kk][ty * 4]);
        float4 b4 = *reinterpret_cast<const float4*>(&Bs[kk][tx * 4]);
        float a[4] = {a4.x, a4.y, a4.z, a4.w};
        float b[4] = {b4.x, b4.y, b4.z, b4.w};
        #pragma unroll
        for (int i = 0; i < 4; ++i)
            #pragma unroll
            for (int j = 0; j < 4; ++j)
                acc[i][j] += a[i] * b[j];
    }

    #pragma unroll
    for (int i = 0; i < 4; ++i) {
        float4 r;
        r.x = acc[i][0] * 0.125f; r.y = acc[i][1] * 0.125f;
        r.z = acc[i][2] * 0.125f; r.w = acc[i][3] * 0.125f;
        *reinterpret_cast<float4*>(att + ((size_t)l * T_ + iBase + ty * 4 + i) * T_ + jBase + tx * 4) = r;
    }
}

// ---------- per-row exact top-256 select; rewrite row as weights w=kept?exp(s)-1:0; denom ----------
__global__ __launch_bounds__(256) void k_select(float* __restrict__ att, float* __restrict__ denom)
{
    const int row = blockIdx.x;                 // chunk-local row: l*T + i
    float* rp = att + (size_t)row * T_;
    const int tid = threadIdx.x;

    __shared__ unsigned int hist[256];
    __shared__ int ss[256];
    __shared__ unsigned int sb[2];
    __shared__ float fden;

    float4 v4 = reinterpret_cast<const float4*>(rp)[tid];
    float s[4] = {v4.x, v4.y, v4.z, v4.w};
    unsigned int u[4];
    #pragma unroll
    for (int e = 0; e < 4; ++e) u[e] = f2u(s[e]);

    unsigned int prefix = 0;
    int kk = TOPK_;
    for (int p = 0; p < 4; ++p) {
        const int shift = 24 - 8 * p;
        hist[tid] = 0;
        __syncthreads();
        #pragma unroll
        for (int e = 0; e < 4; ++e) {
            bool ok = (p == 0) || ((u[e] >> (shift + 8)) == prefix);
            if (ok) atomicAdd(&hist[(u[e] >> shift) & 255u], 1u);
        }
        __syncthreads();
        ss[tid] = (int)hist[tid];
        __syncthreads();
        // suffix sum: ss[i] = sum_{j>=i} hist[j]
        for (int off = 1; off < 256; off <<= 1) {
            int add = (tid + off < 256) ? ss[tid + off] : 0;
            __syncthreads();
            ss[tid] += add;
            __syncthreads();
        }
        int sme = ss[tid];
        int snext = (tid < 255) ? ss[tid + 1] : 0;
        if (sme >= kk && snext < kk) { sb[0] = (unsigned)tid; sb[1] = (unsigned)(kk - snext); }
        __syncthreads();
        prefix = (prefix << 8) | sb[0];
        kk = (int)sb[1];
        __syncthreads();
    }
    const unsigned int uthr = prefix;
    const int budget = kk;   // number of ==thr elements to keep (index order)

    // tie ranks in index order (thread t owns elements 4t..4t+3, contiguous)
    int tloc = 0;
    #pragma unroll
    for (int e = 0; e < 4; ++e) tloc += (u[e] == uthr) ? 1 : 0;
    ss[tid] = tloc;
    __syncthreads();
    for (int off = 1; off < 256; off <<= 1) {
        int add = (tid >= off) ? ss[tid - off] : 0;
        __syncthreads();
        ss[tid] += add;
        __syncthreads();
    }
    int run = ss[tid] - tloc;   // exclusive prefix of tie count

    if (tid == 0) fden = 0.0f;
    __syncthreads();

    float wr[4];
    float wsum = 0.0f;
    #pragma unroll
    for (int e = 0; e < 4; ++e) {
        float w = 0.0f;
        if (u[e] > uthr) {
            w = expf(s[e]) - 1.0f;
        } else if (u[e] == uthr) {
            if (run < budget) w = expf(s[e]) - 1.0f;
            run++;
        }
        wr[e] = w;
        wsum += w;
    }
    #pragma unroll
    for (int off = 32; off > 0; off >>= 1) wsum += __shfl_down(wsum, off);
    if ((tid & 63) == 0) atomicAdd(&fden, wsum);

    float4 wv4; wv4.x = wr[0]; wv4.y = wr[1]; wv4.z = wr[2]; wv4.w = wr[3];
    reinterpret_cast<float4*>(rp)[tid] = wv4;
    __syncthreads();
    if (tid == 0) denom[row] = fden + (float)T_;
}

// ---------- y[g,i,d] = (sum_j W[l,i,j] * V[g,j,d] + Vsum[g,d]) / denom[l,i] ----------
__global__ __launch_bounds__(256) void k_pv(const float* __restrict__ Wt, const float* __restrict__ V,
                                            const float* __restrict__ Vsum, const float* __restrict__ denom,
                                            float* __restrict__ Y, int bh0)
{
    const int l = blockIdx.y;
    const int g = bh0 + l;
    const int iBase = blockIdx.x * 64;

    __shared__ float As[16][68];   // [k][i]
    __shared__ float Bs[16][68];   // [k][d]

    const int tid = threadIdx.x;
    const int tx = tid & 15, ty = tid >> 4;
    const int lr = tid >> 2;          // 0..63
    const int lk = (tid & 3) * 4;     // 0,4,8,12
    const int kr = tid >> 4;          // 0..15
    const int dc = (tid & 15) * 4;    // 0..60

    const float* Wrow = Wt + ((size_t)l * T_ + iBase) * T_;
    const float* Vb = V + (size_t)g * T_ * D_;

    float acc[4][4] = {{0.0f}};

    for (int k0 = 0; k0 < T_; k0 += 16) {
        float4 av = *reinterpret_cast<const float4*>(Wrow + (size_t)lr * T_ + k0 + lk);
        As[lk + 0][lr] = av.x; As[lk + 1][lr] = av.y; As[lk + 2][lr] = av.z; As[lk + 3][lr] = av.w;
        float4 bv4 = *reinterpret_cast<const float4*>(Vb + (size_t)(k0 + kr) * D_ + dc);
        *reinterpret_cast<float4*>(&Bs[kr][dc]) = bv4;
        __syncthreads();
        #pragma unroll
        for (int kkk = 0; kkk < 16; ++kkk) {
            float4 a4 = *reinterpret_cast<const float4*>(&As[kkk][ty * 4]);
            float4 b4 = *reinterpret_cast<const float4*>(&Bs[kkk][tx * 4]);
            float a[4] = {a4.x, a4.y, a4.z, a4.w};
            float b[4] = {b4.x, b4.y, b4.z, b4.w};
            #pragma unroll
            for (int i = 0; i < 4; ++i)
                #pragma unroll
                for (int j = 0; j < 4; ++j)
                    acc[i][j] += a[i] * b[j];
        }
        __syncthreads();
    }

    const int d0 = tx * 4;
    #pragma unroll
    for (int i = 0; i < 4; ++i) {
        int ii = iBase + ty * 4 + i;
        float dn = denom[(size_t)l * T_ + ii];
        float inv = 1.0f / dn;
        float4 r;
        r.x = (acc[i][0] + Vsum[g * D_ + d0 + 0]) * inv;
        r.y = (acc[i][1] + Vsum[g * D_ + d0 + 1]) * inv;
        r.z = (acc[i][2] + Vsum[g * D_ + d0 + 2]) * inv;
        r.w = (acc[i][3] + Vsum[g * D_ + d0 + 3]) * inv;
        *reinterpret_cast<float4*>(Y + ((size_t)g * T_ + ii) * D_ + d0) = r;
    }
}

// ---------- out[b,t,o] = bias[o] + sum_{h,d} Y[b,h,t,d] * wo[o,hd]*mo[o,hd] ----------
__global__ __launch_bounds__(256) void k_oproj(
    const float* __restrict__ Y, const float* __restrict__ W, const float* __restrict__ M,
    const float* __restrict__ bias, float* __restrict__ out)
{
    __shared__ float As[16][132];
    __shared__ float Bs[16][132];

    const int tid = threadIdx.x;
    const int tx = tid & 15;
    const int ty = tid >> 4;
    const int mBase = blockIdx.y * 128;
    const int nBase = blockIdx.x * 128;

    float acc[8][8];
    #pragma unroll
    for (int i = 0; i < 8; ++i)
        #pragma unroll
        for (int j = 0; j < 8; ++j) acc[i][j] = 0.0f;

    for (int k0 = 0; k0 < C_; k0 += 16) {
        #pragma unroll
        for (int p = 0; p < 2; ++p) {
            int f = p * 256 + tid;
            int row = f >> 2;
            int kc  = (f & 3) * 4;
            int m = mBase + row;
            int b_i = m >> 10;
            int t_i = m & 1023;
            int kidx = k0 + kc;
            float4 av = *reinterpret_cast<const float4*>(
                Y + (((size_t)b_i * H_ + (kidx >> 6)) * T_ + t_i) * D_ + (kidx & 63));
            size_t boff = (size_t)(nBase + row) * C_ + k0 + kc;
            float4 wv4 = *reinterpret_cast<const float4*>(W + boff);
            float4 mv4 = *reinterpret_cast<const float4*>(M + boff);
            As[kc + 0][row] = av.x; As[kc + 1][row] = av.y;
            As[kc + 2][row] = av.z; As[kc + 3][row] = av.w;
            Bs[kc + 0][row] = wv4.x * mv4.x; Bs[kc + 1][row] = wv4.y * mv4.y;
            Bs[kc + 2][row] = wv4.z * mv4.z; Bs[kc + 3][row] = wv4.w * mv4.w;
        }
        __syncthreads();
        #pragma unroll
        for (int kk = 0; kk < 16; ++kk) {
            float4 aLo = *reinterpret_cast<const float4*>(&As[kk][ty * 4]);
            float4 aHi = *reinterpret_cast<const float4*>(&As[kk][64 + ty * 4]);
            float4 bLo = *reinterpret_cast<const float4*>(&Bs[kk][tx * 4]);
            float4 bHi = *reinterpret_cast<const float4*>(&Bs[kk][64 + tx * 4]);
            float a[8] = {aLo.x, aLo.y, aLo.z, aLo.w, aHi.x, aHi.y, aHi.z, aHi.w};
            float b[8] = {bLo.x, bLo.y, bLo.z, bLo.w, bHi.x, bHi.y, bHi.z, bHi.w};
            #pragma unroll
            for (int i = 0; i < 8; ++i)
                #pragma unroll
                for (int j = 0; j < 8; ++j)
                    acc[i][j] += a[i] * b[j];
        }
        __syncthreads();
    }

    #pragma unroll
    for (int ih = 0; ih < 2; ++ih) {
        #pragma unroll
        for (int i = 0; i < 4; ++i) {
            int m = mBase + ih * 64 + ty * 4 + i;
            #pragma unroll
            for (int jh = 0; jh < 2; ++jh) {
                int o0 = nBase + jh * 64 + tx * 4;
                float4 r;
                r.x = acc[ih * 4 + i][jh * 4 + 0] + bias[o0 + 0];
                r.y = acc[ih * 4 + i][jh * 4 + 1] + bias[o0 + 1];
                r.z = acc[ih * 4 + i][jh * 4 + 2] + bias[o0 + 2];
                r.w = acc[ih * 4 + i][jh * 4 + 3] + bias[o0 + 3];
                *reinterpret_cast<float4*>(out + (size_t)m * C_ + o0) = r;
            }
        }
    }
}

extern "C" void kernel_launch(void* const* d_in, const int* in_sizes, int n_in,
                              void* d_out, int out_size, void* d_ws, size_t ws_size,
                              hipStream_t stream)
{
    (void)in_sizes; (void)n_in; (void)out_size;

    const float* x  = (const float*)d_in[0];
    const float* wq = (const float*)d_in[1];
    const float* bq = (const float*)d_in[2];
    const float* mq = (const float*)d_in[3];
    const float* wk = (const float*)d_in[4];
    const float* bk = (const float*)d_in[5];
    const float* mk = (const float*)d_in[6];
    const float* wv = (const float*)d_in[7];
    const float* bv = (const float*)d_in[8];
    const float* mv = (const float*)d_in[9];
    const float* wo = (const float*)d_in[10];
    const float* bo = (const float*)d_in[11];
    const float* mo = (const float*)d_in[12];
    float* out = (float*)d_out;

    const size_t NQ = (size_t)B_ * H_ * T_ * D_;   // 4M floats per tensor

    float* Q  = (float*)d_ws;       // also holds y after k_pv (per-slice overwrite after use)
    float* K  = Q + NQ;
    float* V  = K + NQ;
    float* att = V + NQ;

    int CH = 8;
    while (CH > 1) {
        size_t need = (3 * NQ + (size_t)CH * T_ * T_ + (size_t)BH_ * D_ + (size_t)CH * T_) * sizeof(float);
        if (need <= ws_size) break;
        CH >>= 1;
    }
    float* Vsum  = att + (size_t)CH * T_ * T_;
    float* denom = Vsum + BH_ * D_;

    k_qkv<<<dim3(8, 32, 3), dim3(256), 0, stream>>>(x, wq, mq, bq, wk, mk, bk, wv, mv, bv, Q, K, V);
    k_vsum<<<dim3(BH_), dim3(64), 0, stream>>>(V, Vsum);

    for (int bh0 = 0; bh0 < BH_; bh0 += CH) {
        k_qk<<<dim3(16, 16, CH), dim3(256), 0, stream>>>(Q, K, att, bh0);
        k_select<<<dim3(CH * T_), dim3(256), 0, stream>>>(att, denom);
        k_pv<<<dim3(16, CH), dim3(256), 0, stream>>>(att, V, Vsum, denom, Q, bh0);
    }

    k_oproj<<<dim3(8, 32), dim3(256), 0, stream>>>(Q, wo, mo, bo, out);
}

// Round 7
// 1091.468 us; speedup vs baseline: 1.3923x; 1.3923x over previous
//
#include <hip/hip_runtime.h>
#include <math.h>

#define B_ 4
#define T_ 1024
#define C_ 1024
#define H_ 16
#define D_ 64
#define BH_ 64
#define TOPK_ 256

__device__ __forceinline__ unsigned int f2u(float f) {
    unsigned int u = __float_as_uint(f);
    return (u & 0x80000000u) ? ~u : (u | 0x80000000u);
}

// ---------- QKV projection (unchanged): 128x128 tile, BK=16, 8x8 micro ----------
__global__ __launch_bounds__(256) void k_qkv(
    const float* __restrict__ x,
    const float* __restrict__ wq, const float* __restrict__ mq, const float* __restrict__ bq,
    const float* __restrict__ wk, const float* __restrict__ mk, const float* __restrict__ bk,
    const float* __restrict__ wv, const float* __restrict__ mv, const float* __restrict__ bv,
    float* __restrict__ Qo, float* __restrict__ Ko, float* __restrict__ Vo)
{
    const int z = blockIdx.z;
    const float* W    = z == 0 ? wq : (z == 1 ? wk : wv);
    const float* M    = z == 0 ? mq : (z == 1 ? mk : mv);
    const float* bias = z == 0 ? bq : (z == 1 ? bk : bv);
    float* out        = z == 0 ? Qo : (z == 1 ? Ko : Vo);

    __shared__ float As[16][132];
    __shared__ float Bs[16][132];

    const int tid = threadIdx.x;
    const int tx = tid & 15;
    const int ty = tid >> 4;
    const int mBase = blockIdx.y * 128;
    const int nBase = blockIdx.x * 128;

    float acc[8][8];
    #pragma unroll
    for (int i = 0; i < 8; ++i)
        #pragma unroll
        for (int j = 0; j < 8; ++j) acc[i][j] = 0.0f;

    for (int k0 = 0; k0 < C_; k0 += 16) {
        #pragma unroll
        for (int p = 0; p < 2; ++p) {
            int f = p * 256 + tid;
            int row = f >> 2;
            int kc  = (f & 3) * 4;
            float4 av = *reinterpret_cast<const float4*>(x + (size_t)(mBase + row) * C_ + k0 + kc);
            size_t boff = (size_t)(nBase + row) * C_ + k0 + kc;
            float4 wv4 = *reinterpret_cast<const float4*>(W + boff);
            float4 mv4 = *reinterpret_cast<const float4*>(M + boff);
            As[kc + 0][row] = av.x; As[kc + 1][row] = av.y;
            As[kc + 2][row] = av.z; As[kc + 3][row] = av.w;
            Bs[kc + 0][row] = wv4.x * mv4.x; Bs[kc + 1][row] = wv4.y * mv4.y;
            Bs[kc + 2][row] = wv4.z * mv4.z; Bs[kc + 3][row] = wv4.w * mv4.w;
        }
        __syncthreads();
        #pragma unroll
        for (int kk = 0; kk < 16; ++kk) {
            float4 aLo = *reinterpret_cast<const float4*>(&As[kk][ty * 4]);
            float4 aHi = *reinterpret_cast<const float4*>(&As[kk][64 + ty * 4]);
            float4 bLo = *reinterpret_cast<const float4*>(&Bs[kk][tx * 4]);
            float4 bHi = *reinterpret_cast<const float4*>(&Bs[kk][64 + tx * 4]);
            float a[8] = {aLo.x, aLo.y, aLo.z, aLo.w, aHi.x, aHi.y, aHi.z, aHi.w};
            float b[8] = {bLo.x, bLo.y, bLo.z, bLo.w, bHi.x, bHi.y, bHi.z, bHi.w};
            #pragma unroll
            for (int i = 0; i < 8; ++i)
                #pragma unroll
                for (int j = 0; j < 8; ++j)
                    acc[i][j] += a[i] * b[j];
        }
        __syncthreads();
    }

    #pragma unroll
    for (int ih = 0; ih < 2; ++ih) {
        #pragma unroll
        for (int i = 0; i < 4; ++i) {
            int m = mBase + ih * 64 + ty * 4 + i;
            int b_i = m >> 10;
            int t_i = m & 1023;
            #pragma unroll
            for (int jh = 0; jh < 2; ++jh) {
                int o0 = nBase + jh * 64 + tx * 4;
                float4 r;
                r.x = acc[ih * 4 + i][jh * 4 + 0] + bias[o0 + 0];
                r.y = acc[ih * 4 + i][jh * 4 + 1] + bias[o0 + 1];
                r.z = acc[ih * 4 + i][jh * 4 + 2] + bias[o0 + 2];
                r.w = acc[ih * 4 + i][jh * 4 + 3] + bias[o0 + 3];
                *reinterpret_cast<float4*>(out + (((size_t)b_i * H_ + (o0 >> 6)) * T_ + t_i) * D_ + (o0 & 63)) = r;
            }
        }
    }
}

// ---------- Vsum[bh,d] = sum_t V[bh,t,d] ----------
__global__ __launch_bounds__(64) void k_vsum(const float* __restrict__ V, float* __restrict__ Vsum)
{
    const int bh = blockIdx.x;
    const int d  = threadIdx.x;
    const float* p = V + (size_t)bh * T_ * D_ + d;
    float s = 0.0f;
    for (int t = 0; t < T_; ++t) s += p[(size_t)t * D_];
    Vsum[bh * D_ + d] = s;
}

// ---------- QK^T: 128x128 tile, K=64 single shot, 8x8 micro ----------
__global__ __launch_bounds__(256) void k_qk2(const float* __restrict__ Q, const float* __restrict__ Kt,
                                             float* __restrict__ att, int bh0)
{
    const int l = blockIdx.z;
    const int g = bh0 + l;
    const int iBase = blockIdx.y * 128;
    const int jBase = blockIdx.x * 128;

    __shared__ float As[64][132];   // [k][i]
    __shared__ float Bs[64][132];   // [k][j]

    const int tid = threadIdx.x;

    #pragma unroll
    for (int p = 0; p < 8; ++p) {
        int f = p * 256 + tid;
        int row = f >> 4;          // 0..127
        int kc  = (f & 15) * 4;    // 0..60
        float4 qa = *reinterpret_cast<const float4*>(Q  + ((size_t)g * T_ + iBase + row) * D_ + kc);
        float4 ka = *reinterpret_cast<const float4*>(Kt + ((size_t)g * T_ + jBase + row) * D_ + kc);
        As[kc + 0][row] = qa.x; As[kc + 1][row] = qa.y; As[kc + 2][row] = qa.z; As[kc + 3][row] = qa.w;
        Bs[kc + 0][row] = ka.x; Bs[kc + 1][row] = ka.y; Bs[kc + 2][row] = ka.z; Bs[kc + 3][row] = ka.w;
    }
    __syncthreads();

    const int ti = tid >> 4;    // 0..15
    const int tj = tid & 15;    // 0..15

    float acc[8][8];
    #pragma unroll
    for (int i = 0; i < 8; ++i)
        #pragma unroll
        for (int j = 0; j < 8; ++j) acc[i][j] = 0.0f;

    #pragma unroll 8
    for (int kk = 0; kk < 64; ++kk) {
        float4 aLo = *reinterpret_cast<const float4*>(&As[kk][ti * 8]);
        float4 aHi = *reinterpret_cast<const float4*>(&As[kk][ti * 8 + 4]);
        float4 bLo = *reinterpret_cast<const float4*>(&Bs[kk][tj * 8]);
        float4 bHi = *reinterpret_cast<const float4*>(&Bs[kk][tj * 8 + 4]);
        float a[8] = {aLo.x, aLo.y, aLo.z, aLo.w, aHi.x, aHi.y, aHi.z, aHi.w};
        float b[8] = {bLo.x, bLo.y, bLo.z, bLo.w, bHi.x, bHi.y, bHi.z, bHi.w};
        #pragma unroll
        for (int i = 0; i < 8; ++i)
            #pragma unroll
            for (int j = 0; j < 8; ++j)
                acc[i][j] += a[i] * b[j];
    }

    #pragma unroll
    for (int i = 0; i < 8; ++i) {
        int ii = iBase + ti * 8 + i;
        float* op = att + ((size_t)l * T_ + ii) * T_ + jBase + tj * 8;
        float4 r0, r1;
        r0.x = acc[i][0] * 0.125f; r0.y = acc[i][1] * 0.125f;
        r0.z = acc[i][2] * 0.125f; r0.w = acc[i][3] * 0.125f;
        r1.x = acc[i][4] * 0.125f; r1.y = acc[i][5] * 0.125f;
        r1.z = acc[i][6] * 0.125f; r1.w = acc[i][7] * 0.125f;
        *reinterpret_cast<float4*>(op)     = r0;
        *reinterpret_cast<float4*>(op + 4) = r1;
    }
}

// ---------- wave-parallel top-256 select: 1 row per wave, zero block barriers ----------
__global__ __launch_bounds__(256) void k_sel2(float* __restrict__ att, float* __restrict__ denom)
{
    __shared__ unsigned int hist4[4][256];
    const int tid = threadIdx.x;
    const int w = tid >> 6;
    const int l = tid & 63;
    const int row = blockIdx.x * 4 + w;
    float* rp = att + (size_t)row * T_;
    unsigned int* h = hist4[w];

    // lane l owns indices j = e*64 + l  (ascending (e,l) == ascending j)
    float s[16];
    unsigned int u[16];
    #pragma unroll
    for (int e = 0; e < 16; ++e) {
        s[e] = rp[e * 64 + l];
        u[e] = f2u(s[e]);
    }

    unsigned int prefix = 0;
    int kk = TOPK_;
    #pragma unroll
    for (int p = 0; p < 4; ++p) {
        const int shift = 24 - 8 * p;
        #pragma unroll
        for (int m = 0; m < 4; ++m) h[l * 4 + m] = 0u;
        __builtin_amdgcn_wave_barrier();
        #pragma unroll
        for (int e = 0; e < 16; ++e) {
            bool ok = (p == 0) || ((u[e] >> (shift + 8)) == prefix);
            if (ok) atomicAdd(&h[(u[e] >> shift) & 255u], 1u);
        }
        __builtin_amdgcn_wave_barrier();
        unsigned int h0 = h[l * 4 + 0], h1 = h[l * 4 + 1], h2 = h[l * 4 + 2], h3 = h[l * 4 + 3];
        unsigned int L3v = h3;
        unsigned int L2v = h2 + L3v;
        unsigned int L1v = h1 + L2v;
        unsigned int L0v = h0 + L1v;          // lane sum
        // inclusive suffix scan of lane sums: S = sum over lanes >= l
        unsigned int S = L0v;
        #pragma unroll
        for (int off = 1; off < 64; off <<= 1) {
            unsigned int t = (unsigned int)__shfl_down((int)S, off);
            if (l + off < 64) S += t;
        }
        unsigned int Snext = S - L0v;         // sum over lanes > l
        unsigned int ssv[4] = {Snext + L0v, Snext + L1v, Snext + L2v, Snext + L3v};
        unsigned int ssn[4] = {Snext + L1v, Snext + L2v, Snext + L3v, Snext};
        unsigned int enc = 0;
        #pragma unroll
        for (int m = 0; m < 4; ++m) {
            if ((int)ssv[m] >= kk && (int)ssn[m] < kk)
                enc = ((unsigned int)(l * 4 + m) << 16) | (unsigned int)(kk - (int)ssn[m]);
        }
        #pragma unroll
        for (int off = 1; off < 64; off <<= 1) enc |= (unsigned int)__shfl_xor((int)enc, off);
        prefix = (prefix << 8) | (enc >> 16);
        kk = (int)(enc & 0xffffu);
    }

    const unsigned int uthr = prefix;
    const int budget = kk;

    // tie ranks in ascending j order via ballots
    const unsigned long long below = (l == 0) ? 0ull : ((1ull << l) - 1ull);
    int base = 0;
    float wsum = 0.0f;
    float wr[16];
    #pragma unroll
    for (int e = 0; e < 16; ++e) {
        bool tie = (u[e] == uthr);
        unsigned long long m = __ballot(tie);
        int rank = base + __popcll(m & below);
        float wv = 0.0f;
        if (u[e] > uthr) wv = expf(s[e]) - 1.0f;
        else if (tie && rank < budget) wv = expf(s[e]) - 1.0f;
        wr[e] = wv;
        wsum += wv;
        base += __popcll(m);
    }
    #pragma unroll
    for (int off = 32; off > 0; off >>= 1) wsum += __shfl_xor(wsum, off);

    #pragma unroll
    for (int e = 0; e < 16; ++e) rp[e * 64 + l] = wr[e];
    if (l == 0) denom[row] = wsum + (float)T_;
}

// ---------- PV: 256x64 tile, BK=32, 8x8 micro ----------
__global__ __launch_bounds__(256) void k_pv2(const float* __restrict__ Wt, const float* __restrict__ V,
                                             const float* __restrict__ Vsum, const float* __restrict__ denom,
                                             float* __restrict__ Y, int bh0)
{
    const int l = blockIdx.y;
    const int g = bh0 + l;
    const int iBase = blockIdx.x * 256;

    __shared__ float As[32][260];   // [k][i]
    __shared__ float Bs[32][68];    // [k][d]

    const int tid = threadIdx.x;
    const int wi = tid >> 3;        // 0..31
    const int wd = tid & 7;         // 0..7

    const float* Wb = Wt + ((size_t)l * T_ + iBase) * T_;
    const float* Vb = V + (size_t)g * T_ * D_;

    float acc[8][8];
    #pragma unroll
    for (int i = 0; i < 8; ++i)
        #pragma unroll
        for (int j = 0; j < 8; ++j) acc[i][j] = 0.0f;

    for (int k0 = 0; k0 < T_; k0 += 32) {
        #pragma unroll
        for (int p = 0; p < 8; ++p) {
            int f = p * 256 + tid;
            int row = f >> 3;        // 0..255
            int kc  = (f & 7) * 4;   // 0..28
            float4 a = *reinterpret_cast<const float4*>(Wb + (size_t)row * T_ + k0 + kc);
            As[kc + 0][row] = a.x; As[kc + 1][row] = a.y;
            As[kc + 2][row] = a.z; As[kc + 3][row] = a.w;
        }
        #pragma unroll
        for (int p = 0; p < 2; ++p) {
            int f = p * 256 + tid;
            int kr = f >> 4;         // 0..31
            int d4 = (f & 15) * 4;   // 0..60
            *reinterpret_cast<float4*>(&Bs[kr][d4]) =
                *reinterpret_cast<const float4*>(Vb + (size_t)(k0 + kr) * D_ + d4);
        }
        __syncthreads();
        #pragma unroll
        for (int kk = 0; kk < 32; ++kk) {
            float4 aLo = *reinterpret_cast<const float4*>(&As[kk][wi * 8]);
            float4 aHi = *reinterpret_cast<const float4*>(&As[kk][wi * 8 + 4]);
            float4 bLo = *reinterpret_cast<const float4*>(&Bs[kk][wd * 8]);
            float4 bHi = *reinterpret_cast<const float4*>(&Bs[kk][wd * 8 + 4]);
            float a[8] = {aLo.x, aLo.y, aLo.z, aLo.w, aHi.x, aHi.y, aHi.z, aHi.w};
            float b[8] = {bLo.x, bLo.y, bLo.z, bLo.w, bHi.x, bHi.y, bHi.z, bHi.w};
            #pragma unroll
            for (int i = 0; i < 8; ++i)
                #pragma unroll
                for (int j = 0; j < 8; ++j)
                    acc[i][j] += a[i] * b[j];
        }
        __syncthreads();
    }

    float4 vs0 = *reinterpret_cast<const float4*>(Vsum + g * D_ + wd * 8);
    float4 vs1 = *reinterpret_cast<const float4*>(Vsum + g * D_ + wd * 8 + 4);
    #pragma unroll
    for (int i = 0; i < 8; ++i) {
        int ii = iBase + wi * 8 + i;
        float inv = 1.0f / denom[(size_t)l * T_ + ii];
        float4 r0, r1;
        r0.x = (acc[i][0] + vs0.x) * inv; r0.y = (acc[i][1] + vs0.y) * inv;
        r0.z = (acc[i][2] + vs0.z) * inv; r0.w = (acc[i][3] + vs0.w) * inv;
        r1.x = (acc[i][4] + vs1.x) * inv; r1.y = (acc[i][5] + vs1.y) * inv;
        r1.z = (acc[i][6] + vs1.z) * inv; r1.w = (acc[i][7] + vs1.w) * inv;
        float* op = Y + ((size_t)g * T_ + ii) * D_ + wd * 8;
        *reinterpret_cast<float4*>(op)     = r0;
        *reinterpret_cast<float4*>(op + 4) = r1;
    }
}

// ---------- output projection (unchanged) ----------
__global__ __launch_bounds__(256) void k_oproj(
    const float* __restrict__ Y, const float* __restrict__ W, const float* __restrict__ M,
    const float* __restrict__ bias, float* __restrict__ out)
{
    __shared__ float As[16][132];
    __shared__ float Bs[16][132];

    const int tid = threadIdx.x;
    const int tx = tid & 15;
    const int ty = tid >> 4;
    const int mBase = blockIdx.y * 128;
    const int nBase = blockIdx.x * 128;

    float acc[8][8];
    #pragma unroll
    for (int i = 0; i < 8; ++i)
        #pragma unroll
        for (int j = 0; j < 8; ++j) acc[i][j] = 0.0f;

    for (int k0 = 0; k0 < C_; k0 += 16) {
        #pragma unroll
        for (int p = 0; p < 2; ++p) {
            int f = p * 256 + tid;
            int row = f >> 2;
            int kc  = (f & 3) * 4;
            int m = mBase + row;
            int b_i = m >> 10;
            int t_i = m & 1023;
            int kidx = k0 + kc;
            float4 av = *reinterpret_cast<const float4*>(
                Y + (((size_t)b_i * H_ + (kidx >> 6)) * T_ + t_i) * D_ + (kidx & 63));
            size_t boff = (size_t)(nBase + row) * C_ + k0 + kc;
            float4 wv4 = *reinterpret_cast<const float4*>(W + boff);
            float4 mv4 = *reinterpret_cast<const float4*>(M + boff);
            As[kc + 0][row] = av.x; As[kc + 1][row] = av.y;
            As[kc + 2][row] = av.z; As[kc + 3][row] = av.w;
            Bs[kc + 0][row] = wv4.x * mv4.x; Bs[kc + 1][row] = wv4.y * mv4.y;
            Bs[kc + 2][row] = wv4.z * mv4.z; Bs[kc + 3][row] = wv4.w * mv4.w;
        }
        __syncthreads();
        #pragma unroll
        for (int kk = 0; kk < 16; ++kk) {
            float4 aLo = *reinterpret_cast<const float4*>(&As[kk][ty * 4]);
            float4 aHi = *reinterpret_cast<const float4*>(&As[kk][64 + ty * 4]);
            float4 bLo = *reinterpret_cast<const float4*>(&Bs[kk][tx * 4]);
            float4 bHi = *reinterpret_cast<const float4*>(&Bs[kk][64 + tx * 4]);
            float a[8] = {aLo.x, aLo.y, aLo.z, aLo.w, aHi.x, aHi.y, aHi.z, aHi.w};
            float b[8] = {bLo.x, bLo.y, bLo.z, bLo.w, bHi.x, bHi.y, bHi.z, bHi.w};
            #pragma unroll
            for (int i = 0; i < 8; ++i)
                #pragma unroll
                for (int j = 0; j < 8; ++j)
                    acc[i][j] += a[i] * b[j];
        }
        __syncthreads();
    }

    #pragma unroll
    for (int ih = 0; ih < 2; ++ih) {
        #pragma unroll
        for (int i = 0; i < 4; ++i) {
            int m = mBase + ih * 64 + ty * 4 + i;
            #pragma unroll
            for (int jh = 0; jh < 2; ++jh) {
                int o0 = nBase + jh * 64 + tx * 4;
                float4 r;
                r.x = acc[ih * 4 + i][jh * 4 + 0] + bias[o0 + 0];
                r.y = acc[ih * 4 + i][jh * 4 + 1] + bias[o0 + 1];
                r.z = acc[ih * 4 + i][jh * 4 + 2] + bias[o0 + 2];
                r.w = acc[ih * 4 + i][jh * 4 + 3] + bias[o0 + 3];
                *reinterpret_cast<float4*>(out + (size_t)m * C_ + o0) = r;
            }
        }
    }
}

extern "C" void kernel_launch(void* const* d_in, const int* in_sizes, int n_in,
                              void* d_out, int out_size, void* d_ws, size_t ws_size,
                              hipStream_t stream)
{
    (void)in_sizes; (void)n_in; (void)out_size;

    const float* x  = (const float*)d_in[0];
    const float* wq = (const float*)d_in[1];
    const float* bq = (const float*)d_in[2];
    const float* mq = (const float*)d_in[3];
    const float* wk = (const float*)d_in[4];
    const float* bk = (const float*)d_in[5];
    const float* mk = (const float*)d_in[6];
    const float* wv = (const float*)d_in[7];
    const float* bv = (const float*)d_in[8];
    const float* mv = (const float*)d_in[9];
    const float* wo = (const float*)d_in[10];
    const float* bo = (const float*)d_in[11];
    const float* mo = (const float*)d_in[12];
    float* out = (float*)d_out;

    const size_t NQ = (size_t)B_ * H_ * T_ * D_;   // 4M floats per tensor

    float* Q  = (float*)d_ws;       // Y aliases Q slice-by-slice after consumption
    float* K  = Q + NQ;
    float* V  = K + NQ;
    float* att = V + NQ;

    int CH = 64;
    while (CH > 1) {
        size_t need = (3 * NQ + (size_t)CH * T_ * T_ + (size_t)BH_ * D_ + (size_t)CH * T_) * sizeof(float);
        if (need <= ws_size) break;
        CH >>= 1;
    }
    float* Vsum  = att + (size_t)CH * T_ * T_;
    float* denom = Vsum + BH_ * D_;

    k_qkv<<<dim3(8, 32, 3), dim3(256), 0, stream>>>(x, wq, mq, bq, wk, mk, bk, wv, mv, bv, Q, K, V);
    k_vsum<<<dim3(BH_), dim3(64), 0, stream>>>(V, Vsum);

    for (int bh0 = 0; bh0 < BH_; bh0 += CH) {
        k_qk2<<<dim3(8, 8, CH), dim3(256), 0, stream>>>(Q, K, att, bh0);
        k_sel2<<<dim3(CH * T_ / 4), dim3(256), 0, stream>>>(att, denom);
        k_pv2<<<dim3(4, CH), dim3(256), 0, stream>>>(att, V, Vsum, denom, Q, bh0);
    }

    k_oproj<<<dim3(8, 32), dim3(256), 0, stream>>>(Q, wo, mo, bo, out);
}

// Round 11
// 737.075 us; speedup vs baseline: 2.0617x; 1.4808x over previous
//
#include <hip/hip_runtime.h>
#include <math.h>

#define B_ 4
#define T_ 1024
#define C_ 1024
#define H_ 16
#define D_ 64
#define BH_ 64
#define TOPK_ 256

typedef __attribute__((ext_vector_type(8))) short short8v;
typedef __attribute__((ext_vector_type(4))) float f32x4;

__device__ __forceinline__ unsigned int f2u(float f) {
    unsigned int u = __float_as_uint(f);
    return (u & 0x80000000u) ? ~u : (u | 0x80000000u);
}

__device__ __forceinline__ unsigned short f2bf(float f) {
    unsigned int u = __float_as_uint(f);
    u = u + 0x7fffu + ((u >> 16) & 1u);   // RNE
    return (unsigned short)(u >> 16);
}

// ---------- cast x and the 4 masked weight matrices to bf16 ----------
__global__ __launch_bounds__(256) void k_prep(
    const float* __restrict__ x,
    const float* __restrict__ wq, const float* __restrict__ mq,
    const float* __restrict__ wk, const float* __restrict__ mk,
    const float* __restrict__ wv, const float* __restrict__ mv,
    const float* __restrict__ wo, const float* __restrict__ mo,
    unsigned short* __restrict__ xb, unsigned short* __restrict__ wb)
{
    const int NX4 = (B_ * T_ * C_) / 4;       // 1M float4 of x
    const int NW4 = (4 * C_ * C_) / 4;        // 1M float4 of weights
    int stride = gridDim.x * blockDim.x;
    for (int v = blockIdx.x * blockDim.x + threadIdx.x; v < NX4 + NW4; v += stride) {
        if (v < NX4) {
            float4 f = reinterpret_cast<const float4*>(x)[v];
            ushort4 o;
            o.x = f2bf(f.x); o.y = f2bf(f.y); o.z = f2bf(f.z); o.w = f2bf(f.w);
            reinterpret_cast<ushort4*>(xb)[v] = o;
        } else {
            int vv = v - NX4;
            int z = vv >> 18;                 // 262144 float4 per C_*C_ matrix
            int rem = vv & 262143;
            const float* W; const float* M;
            if (z == 0)      { W = wq; M = mq; }
            else if (z == 1) { W = wk; M = mk; }
            else if (z == 2) { W = wv; M = mv; }
            else             { W = wo; M = mo; }
            float4 fw = reinterpret_cast<const float4*>(W)[rem];
            float4 fm = reinterpret_cast<const float4*>(M)[rem];
            ushort4 o;
            o.x = f2bf(fw.x * fm.x); o.y = f2bf(fw.y * fm.y);
            o.z = f2bf(fw.z * fm.z); o.w = f2bf(fw.w * fm.w);
            reinterpret_cast<ushort4*>(wb + (size_t)z * C_ * C_)[rem] = o;
        }
    }
}

// ---------- cast y (in Q buffer, [b,h,t,d]) to bf16 ----------
__global__ __launch_bounds__(256) void k_cast_y(const float* __restrict__ y, unsigned short* __restrict__ yb)
{
    const int N4 = (B_ * H_ * T_ * D_) / 4;
    int stride = gridDim.x * blockDim.x;
    for (int v = blockIdx.x * blockDim.x + threadIdx.x; v < N4; v += stride) {
        float4 f = reinterpret_cast<const float4*>(y)[v];
        ushort4 o;
        o.x = f2bf(f.x); o.y = f2bf(f.y); o.z = f2bf(f.z); o.w = f2bf(f.w);
        reinterpret_cast<ushort4*>(yb)[v] = o;
    }
}

// ---------- QKV projection via MFMA bf16: C = Xb @ Wb^T + bias, remap to [b,h,t,d] ----------
// 128x128 tile, BK=32, 4 waves x (4x4 frags of 16x16x32)
__global__ __launch_bounds__(256) void k_gemm_qkv(
    const unsigned short* __restrict__ xb,   // [4096][1024] bf16
    const unsigned short* __restrict__ wb,   // [3][1024][1024] bf16 (masked)
    const float* __restrict__ bq, const float* __restrict__ bk, const float* __restrict__ bv,
    float* __restrict__ Qo, float* __restrict__ Ko, float* __restrict__ Vo)
{
    const int z = blockIdx.z;
    const unsigned short* W = wb + (size_t)z * C_ * C_;
    const float* bias = z == 0 ? bq : (z == 1 ? bk : bv);
    float* out        = z == 0 ? Qo : (z == 1 ? Ko : Vo);

    __shared__ unsigned short As[128 * 40];   // [m][k], stride 40 (80B, 16B-aligned rows, ~2-way banks)
    __shared__ unsigned short Bs[128 * 40];   // [n][k]

    const int tid = threadIdx.x;
    const int mBase = blockIdx.y * 128;
    const int nBase = blockIdx.x * 128;
    const int w  = tid >> 6;
    const int l  = tid & 63;
    const int wm = (w >> 1) * 64;
    const int wn = (w & 1) * 64;
    const int lr = l & 15;
    const int lg = l >> 4;

    f32x4 acc[4][4];
    #pragma unroll
    for (int mi = 0; mi < 4; ++mi)
        #pragma unroll
        for (int ni = 0; ni < 4; ++ni)
            acc[mi][ni] = (f32x4){0.f, 0.f, 0.f, 0.f};

    for (int k0 = 0; k0 < C_; k0 += 32) {
        #pragma unroll
        for (int p = 0; p < 2; ++p) {
            int q = p * 256 + tid;
            int row = q >> 2;
            int kc  = (q & 3) * 8;
            *reinterpret_cast<int4*>(&As[row * 40 + kc]) =
                *reinterpret_cast<const int4*>(&xb[(size_t)(mBase + row) * C_ + k0 + kc]);
            *reinterpret_cast<int4*>(&Bs[row * 40 + kc]) =
                *reinterpret_cast<const int4*>(&W[(size_t)(nBase + row) * C_ + k0 + kc]);
        }
        __syncthreads();
        short8v a[4], b[4];
        #pragma unroll
        for (int mi = 0; mi < 4; ++mi)
            a[mi] = *reinterpret_cast<const short8v*>(&As[(wm + mi * 16 + lr) * 40 + lg * 8]);
        #pragma unroll
        for (int ni = 0; ni < 4; ++ni)
            b[ni] = *reinterpret_cast<const short8v*>(&Bs[(wn + ni * 16 + lr) * 40 + lg * 8]);
        #pragma unroll
        for (int mi = 0; mi < 4; ++mi)
            #pragma unroll
            for (int ni = 0; ni < 4; ++ni)
                acc[mi][ni] = __builtin_amdgcn_mfma_f32_16x16x32_bf16(a[mi], b[ni], acc[mi][ni], 0, 0, 0);
        __syncthreads();
    }

    // D mapping (m89-verified): col = lane&15, row = (lane>>4)*4 + reg
    #pragma unroll
    for (int mi = 0; mi < 4; ++mi)
        #pragma unroll
        for (int ni = 0; ni < 4; ++ni) {
            int n = nBase + wn + ni * 16 + lr;
            float bv_ = bias[n];
            int h = n >> 6, d = n & 63;
            #pragma unroll
            for (int r = 0; r < 4; ++r) {
                int m = mBase + wm + mi * 16 + lg * 4 + r;
                int b_i = m >> 10, t_i = m & 1023;
                out[(((size_t)b_i * H_ + h) * T_ + t_i) * D_ + d] = acc[mi][ni][r] + bv_;
            }
        }
}

// ---------- O-projection via MFMA bf16: out[m][n] = Yb[m][:] @ Wo^T + bias ----------
__global__ __launch_bounds__(256) void k_gemm_o(
    const unsigned short* __restrict__ yb,   // [b,h,t,d] bf16
    const unsigned short* __restrict__ wo,   // [1024][1024] bf16 (masked)
    const float* __restrict__ bias, float* __restrict__ out)
{
    __shared__ unsigned short As[128 * 40];
    __shared__ unsigned short Bs[128 * 40];

    const int tid = threadIdx.x;
    const int mBase = blockIdx.y * 128;
    const int nBase = blockIdx.x * 128;
    const int w  = tid >> 6;
    const int l  = tid & 63;
    const int wm = (w >> 1) * 64;
    const int wn = (w & 1) * 64;
    const int lr = l & 15;
    const int lg = l >> 4;

    f32x4 acc[4][4];
    #pragma unroll
    for (int mi = 0; mi < 4; ++mi)
        #pragma unroll
        for (int ni = 0; ni < 4; ++ni)
            acc[mi][ni] = (f32x4){0.f, 0.f, 0.f, 0.f};

    for (int k0 = 0; k0 < C_; k0 += 32) {
        #pragma unroll
        for (int p = 0; p < 2; ++p) {
            int q = p * 256 + tid;
            int row = q >> 2;
            int kc  = (q & 3) * 8;
            int m = mBase + row;
            int b_i = m >> 10, t_i = m & 1023;
            int kk = k0 + kc;
            int h = kk >> 6, d = kk & 63;
            *reinterpret_cast<int4*>(&As[row * 40 + kc]) =
                *reinterpret_cast<const int4*>(&yb[(((size_t)b_i * H_ + h) * T_ + t_i) * D_ + d]);
            *reinterpret_cast<int4*>(&Bs[row * 40 + kc]) =
                *reinterpret_cast<const int4*>(&wo[(size_t)(nBase + row) * C_ + k0 + kc]);
        }
        __syncthreads();
        short8v a[4], b[4];
        #pragma unroll
        for (int mi = 0; mi < 4; ++mi)
            a[mi] = *reinterpret_cast<const short8v*>(&As[(wm + mi * 16 + lr) * 40 + lg * 8]);
        #pragma unroll
        for (int ni = 0; ni < 4; ++ni)
            b[ni] = *reinterpret_cast<const short8v*>(&Bs[(wn + ni * 16 + lr) * 40 + lg * 8]);
        #pragma unroll
        for (int mi = 0; mi < 4; ++mi)
            #pragma unroll
            for (int ni = 0; ni < 4; ++ni)
                acc[mi][ni] = __builtin_amdgcn_mfma_f32_16x16x32_bf16(a[mi], b[ni], acc[mi][ni], 0, 0, 0);
        __syncthreads();
    }

    #pragma unroll
    for (int mi = 0; mi < 4; ++mi)
        #pragma unroll
        for (int ni = 0; ni < 4; ++ni) {
            int n = nBase + wn + ni * 16 + lr;
            float bv_ = bias[n];
            #pragma unroll
            for (int r = 0; r < 4; ++r) {
                int m = mBase + wm + mi * 16 + lg * 4 + r;
                out[(size_t)m * C_ + n] = acc[mi][ni][r] + bv_;
            }
        }
}

// ---------- Vsum[bh,d] = sum_t V[bh,t,d] ----------
__global__ __launch_bounds__(64) void k_vsum(const float* __restrict__ V, float* __restrict__ Vsum)
{
    const int bh = blockIdx.x;
    const int d  = threadIdx.x;
    const float* p = V + (size_t)bh * T_ * D_ + d;
    float s = 0.0f;
    for (int t = 0; t < T_; ++t) s += p[(size_t)t * D_];
    Vsum[bh * D_ + d] = s;
}

// ---------- QK^T: 128x128 tile, K=64 single shot, 8x8 micro (unchanged) ----------
__global__ __launch_bounds__(256) void k_qk2(const float* __restrict__ Q, const float* __restrict__ Kt,
                                             float* __restrict__ att, int bh0)
{
    const int l = blockIdx.z;
    const int g = bh0 + l;
    const int iBase = blockIdx.y * 128;
    const int jBase = blockIdx.x * 128;

    __shared__ float As[64][132];
    __shared__ float Bs[64][132];

    const int tid = threadIdx.x;

    #pragma unroll
    for (int p = 0; p < 8; ++p) {
        int f = p * 256 + tid;
        int row = f >> 4;
        int kc  = (f & 15) * 4;
        float4 qa = *reinterpret_cast<const float4*>(Q  + ((size_t)g * T_ + iBase + row) * D_ + kc);
        float4 ka = *reinterpret_cast<const float4*>(Kt + ((size_t)g * T_ + jBase + row) * D_ + kc);
        As[kc + 0][row] = qa.x; As[kc + 1][row] = qa.y; As[kc + 2][row] = qa.z; As[kc + 3][row] = qa.w;
        Bs[kc + 0][row] = ka.x; Bs[kc + 1][row] = ka.y; Bs[kc + 2][row] = ka.z; Bs[kc + 3][row] = ka.w;
    }
    __syncthreads();

    const int ti = tid >> 4;
    const int tj = tid & 15;

    float acc[8][8];
    #pragma unroll
    for (int i = 0; i < 8; ++i)
        #pragma unroll
        for (int j = 0; j < 8; ++j) acc[i][j] = 0.0f;

    #pragma unroll 8
    for (int kk = 0; kk < 64; ++kk) {
        float4 aLo = *reinterpret_cast<const float4*>(&As[kk][ti * 8]);
        float4 aHi = *reinterpret_cast<const float4*>(&As[kk][ti * 8 + 4]);
        float4 bLo = *reinterpret_cast<const float4*>(&Bs[kk][tj * 8]);
        float4 bHi = *reinterpret_cast<const float4*>(&Bs[kk][tj * 8 + 4]);
        float a[8] = {aLo.x, aLo.y, aLo.z, aLo.w, aHi.x, aHi.y, aHi.z, aHi.w};
        float b[8] = {bLo.x, bLo.y, bLo.z, bLo.w, bHi.x, bHi.y, bHi.z, bHi.w};
        #pragma unroll
        for (int i = 0; i < 8; ++i)
            #pragma unroll
            for (int j = 0; j < 8; ++j)
                acc[i][j] += a[i] * b[j];
    }

    #pragma unroll
    for (int i = 0; i < 8; ++i) {
        int ii = iBase + ti * 8 + i;
        float* op = att + ((size_t)l * T_ + ii) * T_ + jBase + tj * 8;
        float4 r0, r1;
        r0.x = acc[i][0] * 0.125f; r0.y = acc[i][1] * 0.125f;
        r0.z = acc[i][2] * 0.125f; r0.w = acc[i][3] * 0.125f;
        r1.x = acc[i][4] * 0.125f; r1.y = acc[i][5] * 0.125f;
        r1.z = acc[i][6] * 0.125f; r1.w = acc[i][7] * 0.125f;
        *reinterpret_cast<float4*>(op)     = r0;
        *reinterpret_cast<float4*>(op + 4) = r1;
    }
}

// ---------- wave-parallel top-256 select (unchanged) ----------
__global__ __launch_bounds__(256) void k_sel2(float* __restrict__ att, float* __restrict__ denom)
{
    __shared__ unsigned int hist4[4][256];
    const int tid = threadIdx.x;
    const int w = tid >> 6;
    const int l = tid & 63;
    const int row = blockIdx.x * 4 + w;
    float* rp = att + (size_t)row * T_;
    unsigned int* h = hist4[w];

    float s[16];
    unsigned int u[16];
    #pragma unroll
    for (int e = 0; e < 16; ++e) {
        s[e] = rp[e * 64 + l];
        u[e] = f2u(s[e]);
    }

    unsigned int prefix = 0;
    int kk = TOPK_;
    #pragma unroll
    for (int p = 0; p < 4; ++p) {
        const int shift = 24 - 8 * p;
        #pragma unroll
        for (int m = 0; m < 4; ++m) h[l * 4 + m] = 0u;
        __builtin_amdgcn_wave_barrier();
        #pragma unroll
        for (int e = 0; e < 16; ++e) {
            bool ok = (p == 0) || ((u[e] >> (shift + 8)) == prefix);
            if (ok) atomicAdd(&h[(u[e] >> shift) & 255u], 1u);
        }
        __builtin_amdgcn_wave_barrier();
        unsigned int h0 = h[l * 4 + 0], h1 = h[l * 4 + 1], h2 = h[l * 4 + 2], h3 = h[l * 4 + 3];
        unsigned int L3v = h3;
        unsigned int L2v = h2 + L3v;
        unsigned int L1v = h1 + L2v;
        unsigned int L0v = h0 + L1v;
        unsigned int S = L0v;
        #pragma unroll
        for (int off = 1; off < 64; off <<= 1) {
            unsigned int t = (unsigned int)__shfl_down((int)S, off);
            if (l + off < 64) S += t;
        }
        unsigned int Snext = S - L0v;
        unsigned int ssv[4] = {Snext + L0v, Snext + L1v, Snext + L2v, Snext + L3v};
        unsigned int ssn[4] = {Snext + L1v, Snext + L2v, Snext + L3v, Snext};
        unsigned int enc = 0;
        #pragma unroll
        for (int m = 0; m < 4; ++m) {
            if ((int)ssv[m] >= kk && (int)ssn[m] < kk)
                enc = ((unsigned int)(l * 4 + m) << 16) | (unsigned int)(kk - (int)ssn[m]);
        }
        #pragma unroll
        for (int off = 1; off < 64; off <<= 1) enc |= (unsigned int)__shfl_xor((int)enc, off);
        prefix = (prefix << 8) | (enc >> 16);
        kk = (int)(enc & 0xffffu);
    }

    const unsigned int uthr = prefix;
    const int budget = kk;

    const unsigned long long below = (l == 0) ? 0ull : ((1ull << l) - 1ull);
    int base = 0;
    float wsum = 0.0f;
    float wr[16];
    #pragma unroll
    for (int e = 0; e < 16; ++e) {
        bool tie = (u[e] == uthr);
        unsigned long long m = __ballot(tie);
        int rank = base + __popcll(m & below);
        float wv = 0.0f;
        if (u[e] > uthr) wv = expf(s[e]) - 1.0f;
        else if (tie && rank < budget) wv = expf(s[e]) - 1.0f;
        wr[e] = wv;
        wsum += wv;
        base += __popcll(m);
    }
    #pragma unroll
    for (int off = 32; off > 0; off >>= 1) wsum += __shfl_xor(wsum, off);

    #pragma unroll
    for (int e = 0; e < 16; ++e) rp[e * 64 + l] = wr[e];
    if (l == 0) denom[row] = wsum + (float)T_;
}

// ---------- PV: 256x64 tile, BK=32, 8x8 micro (unchanged) ----------
__global__ __launch_bounds__(256) void k_pv2(const float* __restrict__ Wt, const float* __restrict__ V,
                                             const float* __restrict__ Vsum, const float* __restrict__ denom,
                                             float* __restrict__ Y, int bh0)
{
    const int l = blockIdx.y;
    const int g = bh0 + l;
    const int iBase = blockIdx.x * 256;

    __shared__ float As[32][260];
    __shared__ float Bs[32][68];

    const int tid = threadIdx.x;
    const int wi = tid >> 3;
    const int wd = tid & 7;

    const float* Wb = Wt + ((size_t)l * T_ + iBase) * T_;
    const float* Vb = V + (size_t)g * T_ * D_;

    float acc[8][8];
    #pragma unroll
    for (int i = 0; i < 8; ++i)
        #pragma unroll
        for (int j = 0; j < 8; ++j) acc[i][j] = 0.0f;

    for (int k0 = 0; k0 < T_; k0 += 32) {
        #pragma unroll
        for (int p = 0; p < 8; ++p) {
            int f = p * 256 + tid;
            int row = f >> 3;
            int kc  = (f & 7) * 4;
            float4 a = *reinterpret_cast<const float4*>(Wb + (size_t)row * T_ + k0 + kc);
            As[kc + 0][row] = a.x; As[kc + 1][row] = a.y;
            As[kc + 2][row] = a.z; As[kc + 3][row] = a.w;
        }
        #pragma unroll
        for (int p = 0; p < 2; ++p) {
            int f = p * 256 + tid;
            int kr = f >> 4;
            int d4 = (f & 15) * 4;
            *reinterpret_cast<float4*>(&Bs[kr][d4]) =
                *reinterpret_cast<const float4*>(Vb + (size_t)(k0 + kr) * D_ + d4);
        }
        __syncthreads();
        #pragma unroll
        for (int kk = 0; kk < 32; ++kk) {
            float4 aLo = *reinterpret_cast<const float4*>(&As[kk][wi * 8]);
            float4 aHi = *reinterpret_cast<const float4*>(&As[kk][wi * 8 + 4]);
            float4 bLo = *reinterpret_cast<const float4*>(&Bs[kk][wd * 8]);
            float4 bHi = *reinterpret_cast<const float4*>(&Bs[kk][wd * 8 + 4]);
            float a[8] = {aLo.x, aLo.y, aLo.z, aLo.w, aHi.x, aHi.y, aHi.z, aHi.w};
            float b[8] = {bLo.x, bLo.y, bLo.z, bLo.w, bHi.x, bHi.y, bHi.z, bHi.w};
            #pragma unroll
            for (int i = 0; i < 8; ++i)
                #pragma unroll
                for (int j = 0; j < 8; ++j)
                    acc[i][j] += a[i] * b[j];
        }
        __syncthreads();
    }

    float4 vs0 = *reinterpret_cast<const float4*>(Vsum + g * D_ + wd * 8);
    float4 vs1 = *reinterpret_cast<const float4*>(Vsum + g * D_ + wd * 8 + 4);
    #pragma unroll
    for (int i = 0; i < 8; ++i) {
        int ii = iBase + wi * 8 + i;
        float inv = 1.0f / denom[(size_t)l * T_ + ii];
        float4 r0, r1;
        r0.x = (acc[i][0] + vs0.x) * inv; r0.y = (acc[i][1] + vs0.y) * inv;
        r0.z = (acc[i][2] + vs0.z) * inv; r0.w = (acc[i][3] + vs0.w) * inv;
        r1.x = (acc[i][4] + vs1.x) * inv; r1.y = (acc[i][5] + vs1.y) * inv;
        r1.z = (acc[i][6] + vs1.z) * inv; r1.w = (acc[i][7] + vs1.w) * inv;
        float* op = Y + ((size_t)g * T_ + ii) * D_ + wd * 8;
        *reinterpret_cast<float4*>(op)     = r0;
        *reinterpret_cast<float4*>(op + 4) = r1;
    }
}

extern "C" void kernel_launch(void* const* d_in, const int* in_sizes, int n_in,
                              void* d_out, int out_size, void* d_ws, size_t ws_size,
                              hipStream_t stream)
{
    (void)in_sizes; (void)n_in; (void)out_size;

    const float* x  = (const float*)d_in[0];
    const float* wq = (const float*)d_in[1];
    const float* bq = (const float*)d_in[2];
    const float* mq = (const float*)d_in[3];
    const float* wk = (const float*)d_in[4];
    const float* bk = (const float*)d_in[5];
    const float* mk = (const float*)d_in[6];
    const float* wv = (const float*)d_in[7];
    const float* bv = (const float*)d_in[8];
    const float* mv = (const float*)d_in[9];
    const float* wo = (const float*)d_in[10];
    const float* bo = (const float*)d_in[11];
    const float* mo = (const float*)d_in[12];
    float* out = (float*)d_out;

    const size_t NQ = (size_t)B_ * H_ * T_ * D_;   // 4M floats per tensor

    float* Q  = (float*)d_ws;       // Y aliases Q after consumption
    float* K  = Q + NQ;
    float* V  = K + NQ;
    float* Vsum  = V + NQ;                          // 4096
    float* denom = Vsum + BH_ * D_;                 // 65536
    unsigned short* xb = (unsigned short*)(denom + (size_t)BH_ * T_);   // 4M bf16
    unsigned short* wb = xb + NQ;                   // 4M bf16 (q,k,v,o)
    unsigned short* yb = wb + 4 * (size_t)C_ * C_;  // 4M bf16
    float* att = (float*)(yb + NQ);

    size_t base_f = 3 * NQ + (size_t)BH_ * D_ + (size_t)BH_ * T_ + 3 * NQ / 2; // floats used before att
    int CH = 64;
    while (CH > 1) {
        size_t need = (base_f + (size_t)CH * T_ * T_) * sizeof(float);
        if (need <= ws_size) break;
        CH >>= 1;
    }

    k_prep<<<dim3(2048), dim3(256), 0, stream>>>(x, wq, mq, wk, mk, wv, mv, wo, mo, xb, wb);
    k_gemm_qkv<<<dim3(8, 32, 3), dim3(256), 0, stream>>>(xb, wb, bq, bk, bv, Q, K, V);
    k_vsum<<<dim3(BH_), dim3(64), 0, stream>>>(V, Vsum);

    for (int bh0 = 0; bh0 < BH_; bh0 += CH) {
        k_qk2<<<dim3(8, 8, CH), dim3(256), 0, stream>>>(Q, K, att, bh0);
        k_sel2<<<dim3(CH * T_ / 4), dim3(256), 0, stream>>>(att, denom);
        k_pv2<<<dim3(4, CH), dim3(256), 0, stream>>>(att, V, Vsum, denom, Q, bh0);
    }

    k_cast_y<<<dim3(1024), dim3(256), 0, stream>>>(Q, yb);
    k_gemm_o<<<dim3(8, 32), dim3(256), 0, stream>>>(yb, wb + 3 * (size_t)C_ * C_, bo, out);
}

// Round 13
// 655.637 us; speedup vs baseline: 2.3178x; 1.1242x over previous
//
#include <hip/hip_runtime.h>
#include <math.h>

#define B_ 4
#define T_ 1024
#define C_ 1024
#define H_ 16
#define D_ 64
#define BH_ 64
#define TOPK_ 256

typedef __attribute__((ext_vector_type(8))) short short8v;
typedef __attribute__((ext_vector_type(4))) float f32x4;

__device__ __forceinline__ unsigned int f2u(float f) {
    unsigned int u = __float_as_uint(f);
    return (u & 0x80000000u) ? ~u : (u | 0x80000000u);
}

__device__ __forceinline__ unsigned short f2bf(float f) {
    unsigned int u = __float_as_uint(f);
    u = u + 0x7fffu + ((u >> 16) & 1u);   // RNE
    return (unsigned short)(u >> 16);
}

// ---------- cast x and the 4 masked weight matrices to bf16 ----------
__global__ __launch_bounds__(256) void k_prep(
    const float* __restrict__ x,
    const float* __restrict__ wq, const float* __restrict__ mq,
    const float* __restrict__ wk, const float* __restrict__ mk,
    const float* __restrict__ wv, const float* __restrict__ mv,
    const float* __restrict__ wo, const float* __restrict__ mo,
    unsigned short* __restrict__ xb, unsigned short* __restrict__ wb)
{
    const int NX4 = (B_ * T_ * C_) / 4;
    const int NW4 = (4 * C_ * C_) / 4;
    int stride = gridDim.x * blockDim.x;
    for (int v = blockIdx.x * blockDim.x + threadIdx.x; v < NX4 + NW4; v += stride) {
        if (v < NX4) {
            float4 f = reinterpret_cast<const float4*>(x)[v];
            ushort4 o;
            o.x = f2bf(f.x); o.y = f2bf(f.y); o.z = f2bf(f.z); o.w = f2bf(f.w);
            reinterpret_cast<ushort4*>(xb)[v] = o;
        } else {
            int vv = v - NX4;
            int z = vv >> 18;
            int rem = vv & 262143;
            const float* W; const float* M;
            if (z == 0)      { W = wq; M = mq; }
            else if (z == 1) { W = wk; M = mk; }
            else if (z == 2) { W = wv; M = mv; }
            else             { W = wo; M = mo; }
            float4 fw = reinterpret_cast<const float4*>(W)[rem];
            float4 fm = reinterpret_cast<const float4*>(M)[rem];
            ushort4 o;
            o.x = f2bf(fw.x * fm.x); o.y = f2bf(fw.y * fm.y);
            o.z = f2bf(fw.z * fm.z); o.w = f2bf(fw.w * fm.w);
            reinterpret_cast<ushort4*>(wb + (size_t)z * C_ * C_)[rem] = o;
        }
    }
}

// ---------- cast y (in Q buffer, [b,h,t,d]) to bf16 ----------
__global__ __launch_bounds__(256) void k_cast_y(const float* __restrict__ y, unsigned short* __restrict__ yb)
{
    const int N4 = (B_ * H_ * T_ * D_) / 4;
    int stride = gridDim.x * blockDim.x;
    for (int v = blockIdx.x * blockDim.x + threadIdx.x; v < N4; v += stride) {
        float4 f = reinterpret_cast<const float4*>(y)[v];
        ushort4 o;
        o.x = f2bf(f.x); o.y = f2bf(f.y); o.z = f2bf(f.z); o.w = f2bf(f.w);
        reinterpret_cast<ushort4*>(yb)[v] = o;
    }
}

// ---------- QKV projection via MFMA bf16 (unchanged) ----------
__global__ __launch_bounds__(256) void k_gemm_qkv(
    const unsigned short* __restrict__ xb,
    const unsigned short* __restrict__ wb,
    const float* __restrict__ bq, const float* __restrict__ bk, const float* __restrict__ bv,
    float* __restrict__ Qo, float* __restrict__ Ko, float* __restrict__ Vo)
{
    const int z = blockIdx.z;
    const unsigned short* W = wb + (size_t)z * C_ * C_;
    const float* bias = z == 0 ? bq : (z == 1 ? bk : bv);
    float* out        = z == 0 ? Qo : (z == 1 ? Ko : Vo);

    __shared__ unsigned short As[128 * 40];
    __shared__ unsigned short Bs[128 * 40];

    const int tid = threadIdx.x;
    const int mBase = blockIdx.y * 128;
    const int nBase = blockIdx.x * 128;
    const int w  = tid >> 6;
    const int l  = tid & 63;
    const int wm = (w >> 1) * 64;
    const int wn = (w & 1) * 64;
    const int lr = l & 15;
    const int lg = l >> 4;

    f32x4 acc[4][4];
    #pragma unroll
    for (int mi = 0; mi < 4; ++mi)
        #pragma unroll
        for (int ni = 0; ni < 4; ++ni)
            acc[mi][ni] = (f32x4){0.f, 0.f, 0.f, 0.f};

    for (int k0 = 0; k0 < C_; k0 += 32) {
        #pragma unroll
        for (int p = 0; p < 2; ++p) {
            int q = p * 256 + tid;
            int row = q >> 2;
            int kc  = (q & 3) * 8;
            *reinterpret_cast<int4*>(&As[row * 40 + kc]) =
                *reinterpret_cast<const int4*>(&xb[(size_t)(mBase + row) * C_ + k0 + kc]);
            *reinterpret_cast<int4*>(&Bs[row * 40 + kc]) =
                *reinterpret_cast<const int4*>(&W[(size_t)(nBase + row) * C_ + k0 + kc]);
        }
        __syncthreads();
        short8v a[4], b[4];
        #pragma unroll
        for (int mi = 0; mi < 4; ++mi)
            a[mi] = *reinterpret_cast<const short8v*>(&As[(wm + mi * 16 + lr) * 40 + lg * 8]);
        #pragma unroll
        for (int ni = 0; ni < 4; ++ni)
            b[ni] = *reinterpret_cast<const short8v*>(&Bs[(wn + ni * 16 + lr) * 40 + lg * 8]);
        #pragma unroll
        for (int mi = 0; mi < 4; ++mi)
            #pragma unroll
            for (int ni = 0; ni < 4; ++ni)
                acc[mi][ni] = __builtin_amdgcn_mfma_f32_16x16x32_bf16(a[mi], b[ni], acc[mi][ni], 0, 0, 0);
        __syncthreads();
    }

    #pragma unroll
    for (int mi = 0; mi < 4; ++mi)
        #pragma unroll
        for (int ni = 0; ni < 4; ++ni) {
            int n = nBase + wn + ni * 16 + lr;
            float bv_ = bias[n];
            int h = n >> 6, d = n & 63;
            #pragma unroll
            for (int r = 0; r < 4; ++r) {
                int m = mBase + wm + mi * 16 + lg * 4 + r;
                int b_i = m >> 10, t_i = m & 1023;
                out[(((size_t)b_i * H_ + h) * T_ + t_i) * D_ + d] = acc[mi][ni][r] + bv_;
            }
        }
}

// ---------- O-projection via MFMA bf16 (unchanged) ----------
__global__ __launch_bounds__(256) void k_gemm_o(
    const unsigned short* __restrict__ yb,
    const unsigned short* __restrict__ wo,
    const float* __restrict__ bias, float* __restrict__ out)
{
    __shared__ unsigned short As[128 * 40];
    __shared__ unsigned short Bs[128 * 40];

    const int tid = threadIdx.x;
    const int mBase = blockIdx.y * 128;
    const int nBase = blockIdx.x * 128;
    const int w  = tid >> 6;
    const int l  = tid & 63;
    const int wm = (w >> 1) * 64;
    const int wn = (w & 1) * 64;
    const int lr = l & 15;
    const int lg = l >> 4;

    f32x4 acc[4][4];
    #pragma unroll
    for (int mi = 0; mi < 4; ++mi)
        #pragma unroll
        for (int ni = 0; ni < 4; ++ni)
            acc[mi][ni] = (f32x4){0.f, 0.f, 0.f, 0.f};

    for (int k0 = 0; k0 < C_; k0 += 32) {
        #pragma unroll
        for (int p = 0; p < 2; ++p) {
            int q = p * 256 + tid;
            int row = q >> 2;
            int kc  = (q & 3) * 8;
            int m = mBase + row;
            int b_i = m >> 10, t_i = m & 1023;
            int kk = k0 + kc;
            int h = kk >> 6, d = kk & 63;
            *reinterpret_cast<int4*>(&As[row * 40 + kc]) =
                *reinterpret_cast<const int4*>(&yb[(((size_t)b_i * H_ + h) * T_ + t_i) * D_ + d]);
            *reinterpret_cast<int4*>(&Bs[row * 40 + kc]) =
                *reinterpret_cast<const int4*>(&wo[(size_t)(nBase + row) * C_ + k0 + kc]);
        }
        __syncthreads();
        short8v a[4], b[4];
        #pragma unroll
        for (int mi = 0; mi < 4; ++mi)
            a[mi] = *reinterpret_cast<const short8v*>(&As[(wm + mi * 16 + lr) * 40 + lg * 8]);
        #pragma unroll
        for (int ni = 0; ni < 4; ++ni)
            b[ni] = *reinterpret_cast<const short8v*>(&Bs[(wn + ni * 16 + lr) * 40 + lg * 8]);
        #pragma unroll
        for (int mi = 0; mi < 4; ++mi)
            #pragma unroll
            for (int ni = 0; ni < 4; ++ni)
                acc[mi][ni] = __builtin_amdgcn_mfma_f32_16x16x32_bf16(a[mi], b[ni], acc[mi][ni], 0, 0, 0);
        __syncthreads();
    }

    #pragma unroll
    for (int mi = 0; mi < 4; ++mi)
        #pragma unroll
        for (int ni = 0; ni < 4; ++ni) {
            int n = nBase + wn + ni * 16 + lr;
            float bv_ = bias[n];
            #pragma unroll
            for (int r = 0; r < 4; ++r) {
                int m = mBase + wm + mi * 16 + lg * 4 + r;
                out[(size_t)m * C_ + n] = acc[mi][ni][r] + bv_;
            }
        }
}

// ---------- Vsum[bh,d] = sum_t V[bh,t,d] ----------
__global__ __launch_bounds__(64) void k_vsum(const float* __restrict__ V, float* __restrict__ Vsum)
{
    const int bh = blockIdx.x;
    const int d  = threadIdx.x;
    const float* p = V + (size_t)bh * T_ * D_ + d;
    float s = 0.0f;
    for (int t = 0; t < T_; ++t) s += p[(size_t)t * D_];
    Vsum[bh * D_ + d] = s;
}

// ---------- QK^T: 128x128 tile, K staged in 2x32 chunks (33.8 KB LDS -> 4 blocks/CU) ----------
__global__ __launch_bounds__(256) void k_qk3(const float* __restrict__ Q, const float* __restrict__ Kt,
                                             float* __restrict__ att, int bh0)
{
    const int l = blockIdx.z;
    const int g = bh0 + l;
    const int iBase = blockIdx.y * 128;
    const int jBase = blockIdx.x * 128;

    __shared__ float As[32][132];   // [k][i]
    __shared__ float Bs[32][132];   // [k][j]

    const int tid = threadIdx.x;
    const int ti = tid >> 4;
    const int tj = tid & 15;

    float acc[8][8];
    #pragma unroll
    for (int i = 0; i < 8; ++i)
        #pragma unroll
        for (int j = 0; j < 8; ++j) acc[i][j] = 0.0f;

    for (int kc0 = 0; kc0 < D_; kc0 += 32) {
        #pragma unroll
        for (int p = 0; p < 4; ++p) {
            int f = p * 256 + tid;
            int row = f >> 3;          // 0..127
            int c0  = (f & 7) * 4;     // 0..28
            float4 qa = *reinterpret_cast<const float4*>(Q  + ((size_t)g * T_ + iBase + row) * D_ + kc0 + c0);
            float4 ka = *reinterpret_cast<const float4*>(Kt + ((size_t)g * T_ + jBase + row) * D_ + kc0 + c0);
            As[c0 + 0][row] = qa.x; As[c0 + 1][row] = qa.y; As[c0 + 2][row] = qa.z; As[c0 + 3][row] = qa.w;
            Bs[c0 + 0][row] = ka.x; Bs[c0 + 1][row] = ka.y; Bs[c0 + 2][row] = ka.z; Bs[c0 + 3][row] = ka.w;
        }
        __syncthreads();

        #pragma unroll 8
        for (int kk = 0; kk < 32; ++kk) {
            float4 aLo = *reinterpret_cast<const float4*>(&As[kk][ti * 8]);
            float4 aHi = *reinterpret_cast<const float4*>(&As[kk][ti * 8 + 4]);
            float4 bLo = *reinterpret_cast<const float4*>(&Bs[kk][tj * 8]);
            float4 bHi = *reinterpret_cast<const float4*>(&Bs[kk][tj * 8 + 4]);
            float a[8] = {aLo.x, aLo.y, aLo.z, aLo.w, aHi.x, aHi.y, aHi.z, aHi.w};
            float b[8] = {bLo.x, bLo.y, bLo.z, bLo.w, bHi.x, bHi.y, bHi.z, bHi.w};
            #pragma unroll
            for (int i = 0; i < 8; ++i)
                #pragma unroll
                for (int j = 0; j < 8; ++j)
                    acc[i][j] += a[i] * b[j];
        }
        __syncthreads();
    }

    #pragma unroll
    for (int i = 0; i < 8; ++i) {
        int ii = iBase + ti * 8 + i;
        float* op = att + ((size_t)l * T_ + ii) * T_ + jBase + tj * 8;
        float4 r0, r1;
        r0.x = acc[i][0] * 0.125f; r0.y = acc[i][1] * 0.125f;
        r0.z = acc[i][2] * 0.125f; r0.w = acc[i][3] * 0.125f;
        r1.x = acc[i][4] * 0.125f; r1.y = acc[i][5] * 0.125f;
        r1.z = acc[i][6] * 0.125f; r1.w = acc[i][7] * 0.125f;
        *reinterpret_cast<float4*>(op)     = r0;
        *reinterpret_cast<float4*>(op + 4) = r1;
    }
}

// ---------- wave-parallel top-256 select (unchanged) ----------
__global__ __launch_bounds__(256) void k_sel2(float* __restrict__ att, float* __restrict__ denom)
{
    __shared__ unsigned int hist4[4][256];
    const int tid = threadIdx.x;
    const int w = tid >> 6;
    const int l = tid & 63;
    const int row = blockIdx.x * 4 + w;
    float* rp = att + (size_t)row * T_;
    unsigned int* h = hist4[w];

    float s[16];
    unsigned int u[16];
    #pragma unroll
    for (int e = 0; e < 16; ++e) {
        s[e] = rp[e * 64 + l];
        u[e] = f2u(s[e]);
    }

    unsigned int prefix = 0;
    int kk = TOPK_;
    #pragma unroll
    for (int p = 0; p < 4; ++p) {
        const int shift = 24 - 8 * p;
        #pragma unroll
        for (int m = 0; m < 4; ++m) h[l * 4 + m] = 0u;
        __builtin_amdgcn_wave_barrier();
        #pragma unroll
        for (int e = 0; e < 16; ++e) {
            bool ok = (p == 0) || ((u[e] >> (shift + 8)) == prefix);
            if (ok) atomicAdd(&h[(u[e] >> shift) & 255u], 1u);
        }
        __builtin_amdgcn_wave_barrier();
        unsigned int h0 = h[l * 4 + 0], h1 = h[l * 4 + 1], h2 = h[l * 4 + 2], h3 = h[l * 4 + 3];
        unsigned int L3v = h3;
        unsigned int L2v = h2 + L3v;
        unsigned int L1v = h1 + L2v;
        unsigned int L0v = h0 + L1v;
        unsigned int S = L0v;
        #pragma unroll
        for (int off = 1; off < 64; off <<= 1) {
            unsigned int t = (unsigned int)__shfl_down((int)S, off);
            if (l + off < 64) S += t;
        }
        unsigned int Snext = S - L0v;
        unsigned int ssv[4] = {Snext + L0v, Snext + L1v, Snext + L2v, Snext + L3v};
        unsigned int ssn[4] = {Snext + L1v, Snext + L2v, Snext + L3v, Snext};
        unsigned int enc = 0;
        #pragma unroll
        for (int m = 0; m < 4; ++m) {
            if ((int)ssv[m] >= kk && (int)ssn[m] < kk)
                enc = ((unsigned int)(l * 4 + m) << 16) | (unsigned int)(kk - (int)ssn[m]);
        }
        #pragma unroll
        for (int off = 1; off < 64; off <<= 1) enc |= (unsigned int)__shfl_xor((int)enc, off);
        prefix = (prefix << 8) | (enc >> 16);
        kk = (int)(enc & 0xffffu);
    }

    const unsigned int uthr = prefix;
    const int budget = kk;

    const unsigned long long below = (l == 0) ? 0ull : ((1ull << l) - 1ull);
    int base = 0;
    float wsum = 0.0f;
    float wr[16];
    #pragma unroll
    for (int e = 0; e < 16; ++e) {
        bool tie = (u[e] == uthr);
        unsigned long long m = __ballot(tie);
        int rank = base + __popcll(m & below);
        float wv = 0.0f;
        if (u[e] > uthr) wv = expf(s[e]) - 1.0f;
        else if (tie && rank < budget) wv = expf(s[e]) - 1.0f;
        wr[e] = wv;
        wsum += wv;
        base += __popcll(m);
    }
    #pragma unroll
    for (int off = 32; off > 0; off >>= 1) wsum += __shfl_xor(wsum, off);

    #pragma unroll
    for (int e = 0; e < 16; ++e) rp[e * 64 + l] = wr[e];
    if (l == 0) denom[row] = wsum + (float)T_;
}

// ---------- PV: 128x64 tile, BK=32, 8x4 micro (512 blocks -> 2 blocks/CU, 8 waves) ----------
__global__ __launch_bounds__(256) void k_pv3(const float* __restrict__ Wt, const float* __restrict__ V,
                                             const float* __restrict__ Vsum, const float* __restrict__ denom,
                                             float* __restrict__ Y, int bh0)
{
    const int l = blockIdx.y;
    const int g = bh0 + l;
    const int iBase = blockIdx.x * 128;

    __shared__ float As[32][132];   // [k][i] for 128 rows
    __shared__ float Bs[32][68];    // [k][d]

    const int tid = threadIdx.x;
    const int ti = tid >> 4;        // 0..15 -> 8 rows each
    const int tj = tid & 15;        // 0..15 -> 4 d each

    const float* Wb = Wt + ((size_t)l * T_ + iBase) * T_;
    const float* Vb = V + (size_t)g * T_ * D_;

    float acc[8][4];
    #pragma unroll
    for (int i = 0; i < 8; ++i)
        #pragma unroll
        for (int j = 0; j < 4; ++j) acc[i][j] = 0.0f;

    for (int k0 = 0; k0 < T_; k0 += 32) {
        // W: 128 rows x 32 k -> 4 float4 per thread
        #pragma unroll
        for (int p = 0; p < 4; ++p) {
            int f = p * 256 + tid;
            int row = f >> 3;        // 0..127
            int kc  = (f & 7) * 4;   // 0..28
            float4 a = *reinterpret_cast<const float4*>(Wb + (size_t)row * T_ + k0 + kc);
            As[kc + 0][row] = a.x; As[kc + 1][row] = a.y;
            As[kc + 2][row] = a.z; As[kc + 3][row] = a.w;
        }
        // V: 32 k x 64 d -> 2 float4 per thread
        #pragma unroll
        for (int p = 0; p < 2; ++p) {
            int f = p * 256 + tid;
            int kr = f >> 4;         // 0..31
            int d4 = (f & 15) * 4;   // 0..60
            *reinterpret_cast<float4*>(&Bs[kr][d4]) =
                *reinterpret_cast<const float4*>(Vb + (size_t)(k0 + kr) * D_ + d4);
        }
        __syncthreads();
        #pragma unroll
        for (int kk = 0; kk < 32; ++kk) {
            float4 aLo = *reinterpret_cast<const float4*>(&As[kk][ti * 8]);
            float4 aHi = *reinterpret_cast<const float4*>(&As[kk][ti * 8 + 4]);
            float4 b4  = *reinterpret_cast<const float4*>(&Bs[kk][tj * 4]);
            float a[8] = {aLo.x, aLo.y, aLo.z, aLo.w, aHi.x, aHi.y, aHi.z, aHi.w};
            float b[4] = {b4.x, b4.y, b4.z, b4.w};
            #pragma unroll
            for (int i = 0; i < 8; ++i)
                #pragma unroll
                for (int j = 0; j < 4; ++j)
                    acc[i][j] += a[i] * b[j];
        }
        __syncthreads();
    }

    float4 vs = *reinterpret_cast<const float4*>(Vsum + g * D_ + tj * 4);
    #pragma unroll
    for (int i = 0; i < 8; ++i) {
        int ii = iBase + ti * 8 + i;
        float inv = 1.0f / denom[(size_t)l * T_ + ii];
        float4 r;
        r.x = (acc[i][0] + vs.x) * inv; r.y = (acc[i][1] + vs.y) * inv;
        r.z = (acc[i][2] + vs.z) * inv; r.w = (acc[i][3] + vs.w) * inv;
        *reinterpret_cast<float4*>(Y + ((size_t)g * T_ + ii) * D_ + tj * 4) = r;
    }
}

extern "C" void kernel_launch(void* const* d_in, const int* in_sizes, int n_in,
                              void* d_out, int out_size, void* d_ws, size_t ws_size,
                              hipStream_t stream)
{
    (void)in_sizes; (void)n_in; (void)out_size;

    const float* x  = (const float*)d_in[0];
    const float* wq = (const float*)d_in[1];
    const float* bq = (const float*)d_in[2];
    const float* mq = (const float*)d_in[3];
    const float* wk = (const float*)d_in[4];
    const float* bk = (const float*)d_in[5];
    const float* mk = (const float*)d_in[6];
    const float* wv = (const float*)d_in[7];
    const float* bv = (const float*)d_in[8];
    const float* mv = (const float*)d_in[9];
    const float* wo = (const float*)d_in[10];
    const float* bo = (const float*)d_in[11];
    const float* mo = (const float*)d_in[12];
    float* out = (float*)d_out;

    const size_t NQ = (size_t)B_ * H_ * T_ * D_;   // 4M floats per tensor

    float* Q  = (float*)d_ws;       // Y aliases Q after consumption
    float* K  = Q + NQ;
    float* V  = K + NQ;
    float* Vsum  = V + NQ;
    float* denom = Vsum + BH_ * D_;
    unsigned short* xb = (unsigned short*)(denom + (size_t)BH_ * T_);
    unsigned short* wb = xb + NQ;
    unsigned short* yb = wb + 4 * (size_t)C_ * C_;
    float* att = (float*)(yb + NQ);

    size_t base_f = 3 * NQ + (size_t)BH_ * D_ + (size_t)BH_ * T_ + 3 * NQ / 2;
    int CH = 64;
    while (CH > 1) {
        size_t need = (base_f + (size_t)CH * T_ * T_) * sizeof(float);
        if (need <= ws_size) break;
        CH >>= 1;
    }

    k_prep<<<dim3(2048), dim3(256), 0, stream>>>(x, wq, mq, wk, mk, wv, mv, wo, mo, xb, wb);
    k_gemm_qkv<<<dim3(8, 32, 3), dim3(256), 0, stream>>>(xb, wb, bq, bk, bv, Q, K, V);
    k_vsum<<<dim3(BH_), dim3(64), 0, stream>>>(V, Vsum);

    for (int bh0 = 0; bh0 < BH_; bh0 += CH) {
        k_qk3<<<dim3(8, 8, CH), dim3(256), 0, stream>>>(Q, K, att, bh0);
        k_sel2<<<dim3(CH * T_ / 4), dim3(256), 0, stream>>>(att, denom);
        k_pv3<<<dim3(8, CH), dim3(256), 0, stream>>>(att, V, Vsum, denom, Q, bh0);
    }

    k_cast_y<<<dim3(1024), dim3(256), 0, stream>>>(Q, yb);
    k_gemm_o<<<dim3(8, 32), dim3(256), 0, stream>>>(yb, wb + 3 * (size_t)C_ * C_, bo, out);
}